// Round 18
// baseline (170.899 us; speedup 1.0000x reference)
//
#include <hip/hip_runtime.h>
#include <hip/hip_bf16.h>

// GroupContrast loss. Per-row reductions instead of the 8192x8192 logits:
//   main pass:   sE_i = sum_{j != i} exp(100*acc_ij - 100)      (dense, MFMA)
//   group pass:  sP_i = sum_pos exp(..), sA_i = sum_pos acc     (sparse, ~1% of pairs)
//   final:  Q = sE - sP;  Z = sP/pc + Q/nc;
//           mlpp = 100*sA/pc - 100 - log(pc) - log(Z);  loss = -T*mean_valid.
//
// ROUND-12 (measured): launch fusion 7->4 enqueues: total 169->161,
// pairgroup 69.3us, VGPR 84, occ 26.4% (2 blocks/CU).
// ROUND-14 (measured): (256,3) NULL — occ/dur/VGPR identical. Pure-VGPR
// occupancy model falsified as lever; residency pinned at 2 blocks/CU.
// ROUND-15: T3/T4 deep pipeline in pairwise path (m201 template, counted
// vmcnt — never 0 in-loop). Old per-jt structure drained vmcnt(0) at every
// __syncthreads, exposing stage latency each tile (m233's stage+vmcnt+bar
// critical path; floor ~27us vs observed 61.6 standalone).
//   3 bufs x 20480B; prologue stages 0,1; per jt:
//     waitcnt vmcnt(5)   (own 5 loads of stage(jt) done; jt+1 in flight)
//     sched_barrier(0); s_barrier   (all waves: stage(jt) landed AND
//                                    compute(jt-1) done -> buf[(jt+2)%3] free)
//     issue stage(jt+2); compute(jt)          [no trailing barrier]
//   last jt uses vmcnt(0). Per-wave count exact: 5 gload_lds per stage,
//   in-order retirement. Group path keeps __syncthreads (unchanged).
// launch_bounds back to (256,2): pipeline needs ~88-92 arch VGPR; (256,3)'s
// 85-cap would spill. LDS 61440+misc -> still 2 blocks/CU.
// pairwise compute internals = round-9 EXACTLY (proven 61.6us).

#define N_ROWS 8192
#define D_PAD 320
#define NG 100
#define TEMP 0.01f
#define NSPLIT 32
#define JCHUNK (N_ROWS / NSPLIT)   // 256
#define IBLK 128                   // pairwise i-rows per block
#define JTILE 32                   // pairwise j-rows per LDS tile
#define NT (JCHUNK / JTILE)        // 8 j-tiles per block
#define LOG2E100 144.2695041f      // 100 * log2(e)

typedef short short8v __attribute__((ext_vector_type(8)));
typedef float float4v __attribute__((ext_vector_type(4)));

__device__ __forceinline__ short f2bf(float f) {
  union { __hip_bfloat16 h; short s; } u;
  u.h = __float2bfloat16(f);
  return u.s;
}

// ---------- setup: W1/W2 -> bf16 Wt[320 n][320 k] transposed ----------
__global__ __launch_bounds__(256) void setup_kernel(
    const float* __restrict__ W1, const float* __restrict__ W2,
    __hip_bfloat16* __restrict__ w1t, __hip_bfloat16* __restrict__ w2t)
{
  int b = blockIdx.x, tid = threadIdx.x;
  int isW2 = (b >= 400);
  int idx = (b - (isW2 ? 400 : 0)) * 256 + tid;
  const float* W = isW2 ? W2 : W1;
  __hip_bfloat16* dst = isW2 ? w2t : w1t;
  int n = idx / D_PAD, k = idx - n * D_PAD;
  float v = (n < 300 && k < 300) ? W[(size_t)k * 300 + n] : 0.0f;
  dst[idx] = __float2bfloat16(v);
}

// ---------- fused MLP + rownorm: x -> fb (bf16, unit rows, padded to 320) ----------
// Block = 64 rows. GEMM1: A=x rows (regs), B=W1t chunks (LDS), h1 -> LDS bf16.
// GEMM2: A=h1 (regs from LDS), B=W2t chunks (LDS), h2 in 80 VGPRs; shuffle-ssq;
// scale; write fb.
__global__ __launch_bounds__(256, 2) void mlp_fused_kernel(
    const float* __restrict__ x, const __hip_bfloat16* __restrict__ w1t,
    const __hip_bfloat16* __restrict__ w2t, const float* __restrict__ b1,
    const float* __restrict__ b2, __hip_bfloat16* __restrict__ fb)
{
  __shared__ __align__(16) short Ws[64 * D_PAD];   // 40960 B, W chunk (swizzled)
  __shared__ __align__(16) short H1[64 * D_PAD];   // 40960 B, h1 tile (swizzled)
  int tid = threadIdx.x;
  int lane = tid & 63, wave = tid >> 6;
  int g = lane >> 4, lc = lane & 15, sw = lc & 7;
  int i0 = blockIdx.x * 64;

  // ---- A-frags from x: rows wave*16+lc, cols kk*32+g*8..+8 (fp32 -> bf16) ----
  short8v afr[10];
  {
    const float* xp = x + (size_t)(i0 + wave * 16 + lc) * 300;
#pragma unroll
    for (int kk = 0; kk < 10; ++kk) {
      int k0 = kk * 32 + g * 8;
      short8v v;
      if (k0 + 8 <= 300) {
        float4 a = *(const float4*)(xp + k0);
        float4 c = *(const float4*)(xp + k0 + 4);
        v[0] = f2bf(a.x); v[1] = f2bf(a.y); v[2] = f2bf(a.z); v[3] = f2bf(a.w);
        v[4] = f2bf(c.x); v[5] = f2bf(c.y); v[6] = f2bf(c.z); v[7] = f2bf(c.w);
      } else if (k0 < 300) {     // k0 == 296: last partial fragment
        float4 a = *(const float4*)(xp + k0);
        v[0] = f2bf(a.x); v[1] = f2bf(a.y); v[2] = f2bf(a.z); v[3] = f2bf(a.w);
        v[4] = 0; v[5] = 0; v[6] = 0; v[7] = 0;
      } else {
        v = short8v{0, 0, 0, 0, 0, 0, 0, 0};
      }
      afr[kk] = v;
    }
  }

  // ---- GEMM1: h1 = relu(x @ W1 + b1) -> H1 (bf16, swizzled) ----
  for (int c = 0; c < 5; ++c) {
    __syncthreads();
    {
      const int4* src = (const int4*)w1t;
      int4* dst = (int4*)Ws;
#pragma unroll
      for (int t = 0; t < 10; ++t) {
        int e = tid + t * 256;
        int r = e / 40, q = e - r * 40;
        dst[r * 40 + (q ^ (r & 7))] = src[(size_t)(c * 64 + r) * 40 + q];
      }
    }
    __syncthreads();
    for (int js = 0; js < 4; ++js) {
      float4v acc = {0.f, 0.f, 0.f, 0.f};
      const short* rowp = Ws + (js * 16 + lc) * D_PAD;
#pragma unroll
      for (int kk = 0; kk < 10; ++kk) {
        short8v bf = *(const short8v*)(rowp + (((g + 4 * kk) ^ sw) << 3));
        acc = __builtin_amdgcn_mfma_f32_16x16x32_bf16(afr[kk], bf, acc, 0, 0, 0);
      }
      int n = c * 64 + js * 16 + lc;
      float bv = (n < 300) ? b1[n] : 0.0f;
#pragma unroll
      for (int r = 0; r < 4; ++r) {
        int row = wave * 16 + g * 4 + r;
        int q = n >> 3;
        H1[row * D_PAD + ((q ^ (row & 7)) << 3) + (n & 7)] =
            f2bf(fmaxf(acc[r] + bv, 0.0f));
      }
    }
  }
  __syncthreads();   // H1 complete

  // ---- h1 A-frags from LDS ----
  short8v hfr[10];
  {
    const short* rp = H1 + (wave * 16 + lc) * D_PAD;
#pragma unroll
    for (int kk = 0; kk < 10; ++kk)
      hfr[kk] = *(const short8v*)(rp + (((g + 4 * kk) ^ sw) << 3));
  }

  // ---- GEMM2: h2 = h1 @ W2 + b2, kept in registers ----
  float4v h2a[5][4];
  for (int c = 0; c < 5; ++c) {
    __syncthreads();
    {
      const int4* src = (const int4*)w2t;
      int4* dst = (int4*)Ws;
#pragma unroll
      for (int t = 0; t < 10; ++t) {
        int e = tid + t * 256;
        int r = e / 40, q = e - r * 40;
        dst[r * 40 + (q ^ (r & 7))] = src[(size_t)(c * 64 + r) * 40 + q];
      }
    }
    __syncthreads();
#pragma unroll
    for (int js = 0; js < 4; ++js) {
      float4v acc = {0.f, 0.f, 0.f, 0.f};
      const short* rowp = Ws + (js * 16 + lc) * D_PAD;
#pragma unroll
      for (int kk = 0; kk < 10; ++kk) {
        short8v bf = *(const short8v*)(rowp + (((g + 4 * kk) ^ sw) << 3));
        acc = __builtin_amdgcn_mfma_f32_16x16x32_bf16(hfr[kk], bf, acc, 0, 0, 0);
      }
      int n = c * 64 + js * 16 + lc;
      float bv = (n < 300) ? b2[n] : 0.0f;
#pragma unroll
      for (int r = 0; r < 4; ++r) acc[r] += bv;   // pad cols: W/b pads=0 -> h2=0
      h2a[c][js] = acc;
    }
  }

  // ---- row ssq (shuffle over the 16 lanes sharing g) + normalize + store ----
  float ssq[4] = {0.f, 0.f, 0.f, 0.f};
#pragma unroll
  for (int c = 0; c < 5; ++c)
#pragma unroll
    for (int js = 0; js < 4; ++js)
#pragma unroll
      for (int r = 0; r < 4; ++r) ssq[r] = fmaf(h2a[c][js][r], h2a[c][js][r], ssq[r]);
  for (int m = 1; m < 16; m <<= 1)
#pragma unroll
    for (int r = 0; r < 4; ++r) ssq[r] += __shfl_xor(ssq[r], m, 64);
  float inv[4];
#pragma unroll
  for (int r = 0; r < 4; ++r) inv[r] = rsqrtf(ssq[r]);
#pragma unroll
  for (int c = 0; c < 5; ++c)
#pragma unroll
    for (int js = 0; js < 4; ++js) {
      int n = c * 64 + js * 16 + lc;
#pragma unroll
      for (int r = 0; r < 4; ++r) {
        int row = i0 + wave * 16 + g * 4 + r;
        fb[(size_t)row * D_PAD + n] = __float2bfloat16(h2a[c][js][r] * inv[r]);
      }
    }
}

// ---------- merged dense pairwise (sE) + sparse group pass (sP,sA) ----------
// blocks [0,NG): group pass (issued first -> run concurrently with pairwise)
// blocks [NG, NG+2048): pairwise, flattened (ibx = pb&63, split = pb>>6)

// Stage a 32-row j-tile with global_load_lds: LDS dest linear (slot e at
// e*16B), XOR swizzle q^(r&7) applied to the per-lane GLOBAL source int4
// index; read side applies the same involution. Dest base wave-uniform +
// lane*16 as HW requires. 32*320*2B = 1280 int4 slots = 5 iters of 256 thr
// => exactly 5 global_load_lds per WAVE per stage (counted-vmcnt unit).
__device__ __forceinline__ void stage_tile32(const short* __restrict__ Fs, int jb,
                                             short* __restrict__ buf, int tid)
{
  int lane = tid & 63;
  int wbase = tid - lane;            // wave*64, wave-uniform
#pragma unroll
  for (int t = 0; t < 5; ++t) {
    int ebase = t * 256 + wbase;     // wave-uniform int4 slot base
    int e = ebase + lane;
    int r = e / 40, qs = e - r * 40;
    int q = qs ^ (r & 7);
    const int4* gsrc = (const int4*)(Fs + (size_t)(jb + r) * D_PAD) + q;
    __builtin_amdgcn_global_load_lds(
        (const __attribute__((address_space(1))) void*)gsrc,
        (__attribute__((address_space(3))) void*)((int4*)buf + ebase),
        16, 0, 0);
  }
}

__global__ __launch_bounds__(256, 2) void pairgroup_kernel(
    const __hip_bfloat16* __restrict__ Fb, const int* __restrict__ labels,
    float* __restrict__ partE, float* __restrict__ sPar,
    float* __restrict__ sAar, int* __restrict__ ticket)
{
  __shared__ __align__(16) short Bs[3][JTILE * D_PAD];  // 61440 B (3-buf rotation)
  __shared__ int memb[256];                             // group path only
  __shared__ int cnt;
  const short* Fs = (const short*)Fb;
  int tid = threadIdx.x;
  int lane = tid & 63, wave = tid >> 6;
  int g = lane >> 4, lc = lane & 15, sw = lc & 7;
  int bx = blockIdx.x;

  if (bx == 0 && tid == 0) atomicExch(ticket, 0);   // reset for final (device-scope)

  if (bx < NG) {
    // ================= group pass (was group_kernel) =================
    short* Bsf = &Bs[0][0];   // used flat as [64][320] (bufs 0+1)
    int grp = bx + 1;
    if (tid == 0) cnt = 0;
    __syncthreads();
    for (int i = tid; i < N_ROWS; i += 256)
      if (labels[i] == grp) { int p = atomicAdd(&cnt, 1); if (p < 256) memb[p] = i; }
    __syncthreads();
    int c = cnt > 256 ? 256 : cnt;
    int nt = (c + 63) >> 6;
    for (int it = 0; it < nt; ++it) {
      short8v afr[10];
      {
        int islot = it * 64 + wave * 16 + lc;
        int arow = memb[islot < c ? islot : 0];
        const short* ap = Fs + (size_t)arow * D_PAD + g * 8;
#pragma unroll
        for (int kk = 0; kk < 10; ++kk) afr[kk] = *(const short8v*)(ap + kk * 32);
      }
      int iglobr[4]; bool ivalid[4];
      for (int r = 0; r < 4; ++r) {
        int islot = it * 64 + wave * 16 + g * 4 + r;
        ivalid[r] = islot < c;
        iglobr[r] = memb[islot < c ? islot : 0];
      }
      float sp[4] = {}, sa[4] = {};
      for (int jt = 0; jt < nt; ++jt) {
        __syncthreads();
        {
          const int4* src = (const int4*)Fs;
          int4* dst = (int4*)Bsf;
#pragma unroll
          for (int t = 0; t < 10; ++t) {
            int e = tid + t * 256;
            int r = e / 40, q = e - r * 40;
            int jslot = jt * 64 + r;
            int grow = memb[jslot < c ? jslot : 0];
            dst[r * 40 + (q ^ (r & 7))] = src[(size_t)grow * 40 + q];
          }
        }
        __syncthreads();
        for (int js = 0; js < 4; ++js) {
          float4v acc = {0.f, 0.f, 0.f, 0.f};
          const short* rowp = Bsf + (js * 16 + lc) * D_PAD;
#pragma unroll
          for (int kk = 0; kk < 10; ++kk) {
            short8v bf = *(const short8v*)(rowp + (((g + 4 * kk) ^ sw) << 3));
            acc = __builtin_amdgcn_mfma_f32_16x16x32_bf16(afr[kk], bf, acc, 0, 0, 0);
          }
          int jslot = jt * 64 + js * 16 + lc;
          bool jv = jslot < c;
          int jglob = memb[jslot < c ? jslot : 0];
#pragma unroll
          for (int r = 0; r < 4; ++r) {
            float a = acc[r];
            float e = exp2f(fmaf(a, LOG2E100, -LOG2E100));
            bool ok = jv && ivalid[r] && (jglob != iglobr[r]);
            sp[r] += ok ? e : 0.f;
            sa[r] += ok ? a : 0.f;
          }
        }
      }
      for (int m = 1; m < 16; m <<= 1)
        for (int r = 0; r < 4; ++r) {
          sp[r] += __shfl_xor(sp[r], m, 64);
          sa[r] += __shfl_xor(sa[r], m, 64);
        }
      if (lc == 0)
        for (int r = 0; r < 4; ++r)
          if (ivalid[r]) { sPar[iglobr[r]] = sp[r]; sAar[iglobr[r]] = sa[r]; }
    }
    return;
  }

  // ========== dense pairwise: T3/T4 counted-vmcnt 3-buffer pipeline =========
  int pb = bx - NG;
  int i0 = (pb & 63) * IBLK;
  int split = pb >> 6;
  int jstart = split * JCHUNK;

  // A-frags for 2 i-subtiles of 64 rows each: 80 VGPRs, resident all kernel
  short8v afr[2][10];
#pragma unroll
  for (int s = 0; s < 2; ++s) {
    const short* ap = Fs + (size_t)(i0 + s * 64 + wave * 16 + lc) * D_PAD + g * 8;
#pragma unroll
    for (int kk = 0; kk < 10; ++kk) afr[s][kk] = *(const short8v*)(ap + kk * 32);
  }
  float sE[2][4] = {};

  // prologue: stage tiles 0 and 1 (10 loads/wave in flight, 5 per tile)
  stage_tile32(Fs, jstart, &Bs[0][0], tid);
  stage_tile32(Fs, jstart + JTILE, &Bs[1][0], tid);

  for (int jt = 0; jt < NT; ++jt) {
    // own stage(jt) loads done (oldest 5 retired, in-order); stage(jt+1) may fly
    if (jt + 1 < NT) {
      asm volatile("s_waitcnt vmcnt(5)" ::: "memory");
    } else {
      asm volatile("s_waitcnt vmcnt(0)" ::: "memory");
    }
    __builtin_amdgcn_sched_barrier(0);      // rule #18: pin nothing above the wait
    __builtin_amdgcn_s_barrier();           // all waves: stage(jt) landed AND
                                            // compute(jt-1) done -> buf[(jt+2)%3] free
    __builtin_amdgcn_sched_barrier(0);
    if (jt + 2 < NT)
      stage_tile32(Fs, jstart + (jt + 2) * JTILE, &Bs[(jt + 2) % 3][0], tid);

    const short* bufp = &Bs[jt % 3][0];
    for (int js = 0; js < JTILE / 16; ++js) {
      float4v acc0 = {0.f, 0.f, 0.f, 0.f}, acc1 = {0.f, 0.f, 0.f, 0.f};
      const short* rowp = bufp + (js * 16 + lc) * D_PAD;
#pragma unroll
      for (int kk = 0; kk < 10; ++kk) {
        short8v bf = *(const short8v*)(rowp + (((g + 4 * kk) ^ sw) << 3));
        acc0 = __builtin_amdgcn_mfma_f32_16x16x32_bf16(afr[0][kk], bf, acc0, 0, 0, 0);
        acc1 = __builtin_amdgcn_mfma_f32_16x16x32_bf16(afr[1][kk], bf, acc1, 0, 0, 0);
      }
      int jb = jstart + jt * JTILE;
      int jgrp = jb + js * 16;   // 16-aligned j-group base
#pragma unroll
      for (int s = 0; s < 2; ++s) {
        float4v acc = s ? acc1 : acc0;
        // diagonal: i-group base == j-group base, then lc == g*4+r inside
        bool dtile = (jgrp == i0 + s * 64 + wave * 16);
#pragma unroll
        for (int r = 0; r < 4; ++r) {
          float e = exp2f(fmaf(acc[r], LOG2E100, -LOG2E100));
          // diagonal excluded here (cannot be reconstructed later without
          // catastrophic cancellation against the ~1e-30-scale sums)
          if (dtile && lc == g * 4 + r) e = 0.0f;
          sE[s][r] += e;
        }
      }
    }
    // no trailing barrier: next iteration's top barrier is the rendezvous
  }

  for (int m = 1; m < 16; m <<= 1)
#pragma unroll
    for (int s = 0; s < 2; ++s)
#pragma unroll
      for (int r = 0; r < 4; ++r) sE[s][r] += __shfl_xor(sE[s][r], m, 64);
  if (lc == 0)
#pragma unroll
    for (int s = 0; s < 2; ++s)
#pragma unroll
      for (int r = 0; r < 4; ++r)
        partE[split * N_ROWS + i0 + s * 64 + wave * 16 + g * 4 + r] = sE[s][r];
}

// ---------- final: per-row combine + last-block ticket scalar reduce ----------
// Per-block LDS histogram of all labels replaces the global counts buffer.
// blk entries padded to 16 floats (64B) so each block's partials live on
// private cache lines; winner reads them with atomicAdd(p,0) (coherence-
// point reads, safe vs non-coherent per-XCD L2s).
__global__ __launch_bounds__(256) void final_kernel(
    const float* __restrict__ partE, const float* __restrict__ sPar,
    const float* __restrict__ sAar, const int* __restrict__ labels,
    float* __restrict__ blk, int* __restrict__ ticket, float* __restrict__ out)
{
  __shared__ int hc[NG + 1];
  __shared__ float rm[256], rv[256];
  __shared__ int winner;
  int tid = threadIdx.x;
  if (tid <= NG) hc[tid] = 0;
  __syncthreads();
  for (int i2 = tid; i2 < N_ROWS; i2 += 256) atomicAdd(&hc[labels[i2]], 1);
  __syncthreads();

  int i = blockIdx.x * 256 + tid;
  float sE = 0.f;
  for (int s = 0; s < NSPLIT; ++s) sE += partE[s * N_ROWS + i];
  float M = 0.f, V = 0.f;
  int pc = hc[labels[i]] - 1;
  if (pc > 0) {
    float P = sPar[i], A = sAar[i];
    float Q = sE - P;
    float pcf = (float)pc, ncf = (float)(N_ROWS - 1 - pc);
    float Z = P / pcf + Q / ncf;
    M = 100.0f * A / pcf - 100.0f - logf(pcf) - logf(Z);
    V = 1.f;
  }
  rm[tid] = M; rv[tid] = V;
  __syncthreads();
  for (int s2 = 128; s2 > 0; s2 >>= 1) {
    if (tid < s2) { rm[tid] += rm[tid + s2]; rv[tid] += rv[tid + s2]; }
    __syncthreads();
  }
  if (tid == 0) {
    blk[blockIdx.x * 16] = rm[0];
    blk[(32 + blockIdx.x) * 16] = rv[0];
    __threadfence();                      // release: partials visible device-wide
    int old = atomicAdd(ticket, 1);
    winner = (old == 31);
  }
  __syncthreads();
  if (winner && tid < 64) {
    float m = (tid < 32) ? atomicAdd(&blk[tid * 16], 0.0f) : 0.f;
    float v = (tid < 32) ? atomicAdd(&blk[(32 + tid) * 16], 0.0f) : 0.f;
    for (int s = 1; s < 32; s <<= 1) {
      m += __shfl_xor(m, s, 64);
      v += __shfl_xor(v, s, 64);
    }
    if (tid == 0) out[0] = (v > 0.f) ? (-TEMP * m / v) : 0.f;
  }
}

extern "C" void kernel_launch(void* const* d_in, const int* in_sizes, int n_in,
                              void* d_out, int out_size, void* d_ws, size_t ws_size,
                              hipStream_t stream)
{
  const float* x  = (const float*)d_in[0];
  const float* W1 = (const float*)d_in[1];
  const float* b1 = (const float*)d_in[2];
  const float* W2 = (const float*)d_in[3];
  const float* b2 = (const float*)d_in[4];
  const int* labels = (const int*)d_in[5];

  char* ws = (char*)d_ws;
  __hip_bfloat16* fb  = (__hip_bfloat16*)(ws);              // 0        .. 5,242,880
  __hip_bfloat16* w1t = (__hip_bfloat16*)(ws + 5242880);    // 204,800
  __hip_bfloat16* w2t = (__hip_bfloat16*)(ws + 5447680);    // 204,800
  float*        partE = (float*)(ws + 5652480);             // 1,048,576
  float*        sPar  = (float*)(ws + 6701056);             // 32,768
  float*        sAar  = (float*)(ws + 6733824);             // 32,768 .. 6,766,592
  // blk/ticket overlay the w1t region (dead after mlp; used only by final)
  float*        blk   = (float*)(ws + 5242880);             // 4,096 B (64 x 16f)
  int*          ticket= (int*)(ws + 5242880 + 4096);        // 4 B

  setup_kernel<<<800, 256, 0, stream>>>(W1, W2, w1t, w2t);
  mlp_fused_kernel<<<N_ROWS / 64, 256, 0, stream>>>(x, w1t, w2t, b1, b2, fb);
  pairgroup_kernel<<<NG + (N_ROWS / IBLK) * NSPLIT, 256, 0, stream>>>(
      fb, labels, partE, sPar, sAar, ticket);
  final_kernel<<<32, 256, 0, stream>>>(partE, sPar, sAar, labels, blk, ticket,
                                       (float*)d_out);
}

// Round 20
// 155.940 us; speedup vs baseline: 1.0959x; 1.0959x over previous
//
#include <hip/hip_runtime.h>
#include <hip/hip_bf16.h>

// GroupContrast loss. Per-row reductions instead of the 8192x8192 logits:
//   main pass:   sE_i = sum_{j != i} exp(100*acc_ij - 100)      (dense, MFMA)
//   group pass:  sP_i = sum_pos exp(..), sA_i = sum_pos acc     (sparse, ~1% of pairs)
//   final:  Q = sE - sP;  Z = sP/pc + Q/nc;
//           mlpp = 100*sA/pc - 100 - log(pc) - log(Z);  loss = -T*mean_valid.
//
// LDS QUANTUM MODEL (rounds 0/4/12/14/18, all consistent): gfx950 allocates
// LDS in 20480B chunks (160K/8); two blocks summing to EXACTLY 160K lose
// residency (runtime sliver):
//   40960 used -> 2ch          -> 2 blocks (r0)
//   42496 used -> 3ch (61440)  -> 2 blocks, 3 DON'T fit (r12; r14 null!)
//   62976 used -> 4ch (81920)  -> 2x = exact 160K -> sliver -> ~1.5 (r18 REGRESSED)
//   81920 used -> 4ch          -> 1 block (r4)
// ROUND-19: block LDS down to <=40960 (2ch) -> 3 blocks/CU legal; (256,3)
// (VGPR 84 proven at this bound, r14). Union trick: pairwise Bs[2][32*320] =
// 40960 exact; group overlays memb/cnt INTO the same 40960 by shrinking its
// j-tile to 48 rows (30720 + 1028 = 31748 <= 40960). Compute structure =
// round-12 EXACTLY (proven 69.3us; r18's deep pipeline regressed -> reverted;
// r12's stage-before-compute + __syncthreads already covers stage latency).

#define N_ROWS 8192
#define D_PAD 320
#define NG 100
#define TEMP 0.01f
#define NSPLIT 32
#define JCHUNK (N_ROWS / NSPLIT)   // 256
#define IBLK 128                   // pairwise i-rows per block
#define JTILE 32                   // pairwise j-rows per LDS tile
#define GJT 48                     // group j-rows per LDS tile (fits union)
#define LOG2E100 144.2695041f      // 100 * log2(e)

typedef short short8v __attribute__((ext_vector_type(8)));
typedef float float4v __attribute__((ext_vector_type(4)));

__device__ __forceinline__ short f2bf(float f) {
  union { __hip_bfloat16 h; short s; } u;
  u.h = __float2bfloat16(f);
  return u.s;
}

// ---------- setup: W1/W2 -> bf16 Wt[320 n][320 k] transposed ----------
__global__ __launch_bounds__(256) void setup_kernel(
    const float* __restrict__ W1, const float* __restrict__ W2,
    __hip_bfloat16* __restrict__ w1t, __hip_bfloat16* __restrict__ w2t)
{
  int b = blockIdx.x, tid = threadIdx.x;
  int isW2 = (b >= 400);
  int idx = (b - (isW2 ? 400 : 0)) * 256 + tid;
  const float* W = isW2 ? W2 : W1;
  __hip_bfloat16* dst = isW2 ? w2t : w1t;
  int n = idx / D_PAD, k = idx - n * D_PAD;
  float v = (n < 300 && k < 300) ? W[(size_t)k * 300 + n] : 0.0f;
  dst[idx] = __float2bfloat16(v);
}

// ---------- fused MLP + rownorm: x -> fb (bf16, unit rows, padded to 320) ----------
// Block = 64 rows. GEMM1: A=x rows (regs), B=W1t chunks (LDS), h1 -> LDS bf16.
// GEMM2: A=h1 (regs from LDS), B=W2t chunks (LDS), h2 in 80 VGPRs; shuffle-ssq;
// scale; write fb.
__global__ __launch_bounds__(256, 2) void mlp_fused_kernel(
    const float* __restrict__ x, const __hip_bfloat16* __restrict__ w1t,
    const __hip_bfloat16* __restrict__ w2t, const float* __restrict__ b1,
    const float* __restrict__ b2, __hip_bfloat16* __restrict__ fb)
{
  __shared__ __align__(16) short Ws[64 * D_PAD];   // 40960 B, W chunk (swizzled)
  __shared__ __align__(16) short H1[64 * D_PAD];   // 40960 B, h1 tile (swizzled)
  int tid = threadIdx.x;
  int lane = tid & 63, wave = tid >> 6;
  int g = lane >> 4, lc = lane & 15, sw = lc & 7;
  int i0 = blockIdx.x * 64;

  // ---- A-frags from x: rows wave*16+lc, cols kk*32+g*8..+8 (fp32 -> bf16) ----
  short8v afr[10];
  {
    const float* xp = x + (size_t)(i0 + wave * 16 + lc) * 300;
#pragma unroll
    for (int kk = 0; kk < 10; ++kk) {
      int k0 = kk * 32 + g * 8;
      short8v v;
      if (k0 + 8 <= 300) {
        float4 a = *(const float4*)(xp + k0);
        float4 c = *(const float4*)(xp + k0 + 4);
        v[0] = f2bf(a.x); v[1] = f2bf(a.y); v[2] = f2bf(a.z); v[3] = f2bf(a.w);
        v[4] = f2bf(c.x); v[5] = f2bf(c.y); v[6] = f2bf(c.z); v[7] = f2bf(c.w);
      } else if (k0 < 300) {     // k0 == 296: last partial fragment
        float4 a = *(const float4*)(xp + k0);
        v[0] = f2bf(a.x); v[1] = f2bf(a.y); v[2] = f2bf(a.z); v[3] = f2bf(a.w);
        v[4] = 0; v[5] = 0; v[6] = 0; v[7] = 0;
      } else {
        v = short8v{0, 0, 0, 0, 0, 0, 0, 0};
      }
      afr[kk] = v;
    }
  }

  // ---- GEMM1: h1 = relu(x @ W1 + b1) -> H1 (bf16, swizzled) ----
  for (int c = 0; c < 5; ++c) {
    __syncthreads();
    {
      const int4* src = (const int4*)w1t;
      int4* dst = (int4*)Ws;
#pragma unroll
      for (int t = 0; t < 10; ++t) {
        int e = tid + t * 256;
        int r = e / 40, q = e - r * 40;
        dst[r * 40 + (q ^ (r & 7))] = src[(size_t)(c * 64 + r) * 40 + q];
      }
    }
    __syncthreads();
    for (int js = 0; js < 4; ++js) {
      float4v acc = {0.f, 0.f, 0.f, 0.f};
      const short* rowp = Ws + (js * 16 + lc) * D_PAD;
#pragma unroll
      for (int kk = 0; kk < 10; ++kk) {
        short8v bf = *(const short8v*)(rowp + (((g + 4 * kk) ^ sw) << 3));
        acc = __builtin_amdgcn_mfma_f32_16x16x32_bf16(afr[kk], bf, acc, 0, 0, 0);
      }
      int n = c * 64 + js * 16 + lc;
      float bv = (n < 300) ? b1[n] : 0.0f;
#pragma unroll
      for (int r = 0; r < 4; ++r) {
        int row = wave * 16 + g * 4 + r;
        int q = n >> 3;
        H1[row * D_PAD + ((q ^ (row & 7)) << 3) + (n & 7)] =
            f2bf(fmaxf(acc[r] + bv, 0.0f));
      }
    }
  }
  __syncthreads();   // H1 complete

  // ---- h1 A-frags from LDS ----
  short8v hfr[10];
  {
    const short* rp = H1 + (wave * 16 + lc) * D_PAD;
#pragma unroll
    for (int kk = 0; kk < 10; ++kk)
      hfr[kk] = *(const short8v*)(rp + (((g + 4 * kk) ^ sw) << 3));
  }

  // ---- GEMM2: h2 = h1 @ W2 + b2, kept in registers ----
  float4v h2a[5][4];
  for (int c = 0; c < 5; ++c) {
    __syncthreads();
    {
      const int4* src = (const int4*)w2t;
      int4* dst = (int4*)Ws;
#pragma unroll
      for (int t = 0; t < 10; ++t) {
        int e = tid + t * 256;
        int r = e / 40, q = e - r * 40;
        dst[r * 40 + (q ^ (r & 7))] = src[(size_t)(c * 64 + r) * 40 + q];
      }
    }
    __syncthreads();
#pragma unroll
    for (int js = 0; js < 4; ++js) {
      float4v acc = {0.f, 0.f, 0.f, 0.f};
      const short* rowp = Ws + (js * 16 + lc) * D_PAD;
#pragma unroll
      for (int kk = 0; kk < 10; ++kk) {
        short8v bf = *(const short8v*)(rowp + (((g + 4 * kk) ^ sw) << 3));
        acc = __builtin_amdgcn_mfma_f32_16x16x32_bf16(hfr[kk], bf, acc, 0, 0, 0);
      }
      int n = c * 64 + js * 16 + lc;
      float bv = (n < 300) ? b2[n] : 0.0f;
#pragma unroll
      for (int r = 0; r < 4; ++r) acc[r] += bv;   // pad cols: W/b pads=0 -> h2=0
      h2a[c][js] = acc;
    }
  }

  // ---- row ssq (shuffle over the 16 lanes sharing g) + normalize + store ----
  float ssq[4] = {0.f, 0.f, 0.f, 0.f};
#pragma unroll
  for (int c = 0; c < 5; ++c)
#pragma unroll
    for (int js = 0; js < 4; ++js)
#pragma unroll
      for (int r = 0; r < 4; ++r) ssq[r] = fmaf(h2a[c][js][r], h2a[c][js][r], ssq[r]);
  for (int m = 1; m < 16; m <<= 1)
#pragma unroll
    for (int r = 0; r < 4; ++r) ssq[r] += __shfl_xor(ssq[r], m, 64);
  float inv[4];
#pragma unroll
  for (int r = 0; r < 4; ++r) inv[r] = rsqrtf(ssq[r]);
#pragma unroll
  for (int c = 0; c < 5; ++c)
#pragma unroll
    for (int js = 0; js < 4; ++js) {
      int n = c * 64 + js * 16 + lc;
#pragma unroll
      for (int r = 0; r < 4; ++r) {
        int row = i0 + wave * 16 + g * 4 + r;
        fb[(size_t)row * D_PAD + n] = __float2bfloat16(h2a[c][js][r] * inv[r]);
      }
    }
}

// ---------- merged dense pairwise (sE) + sparse group pass (sP,sA) ----------
// blocks [0,NG): group pass (issued first -> run concurrently with pairwise)
// blocks [NG, NG+2048): pairwise, flattened (ibx = pb&63, split = pb>>6)
// SHARED MEMORY UNION (exactly 40960 B = 2 LDS chunks -> 3 blocks/CU):
//   pairwise: Bs[2][JTILE*320] shorts      (40960 B)
//   group:    Bsg[GJT*320] shorts (30720) + memb[256] ints @30720 + cnt @31744

// Stage a 32-row j-tile with global_load_lds: LDS dest linear (slot e at
// e*16B), XOR swizzle q^(r&7) applied to the per-lane GLOBAL source int4
// index; read side applies the same involution. Dest base wave-uniform +
// lane*16 as HW requires. 32*320*2B = 1280 int4 slots = 5 iters of 256 thr.
__device__ __forceinline__ void stage_tile32(const short* __restrict__ Fs, int jb,
                                             short* __restrict__ buf, int tid)
{
  int lane = tid & 63;
  int wbase = tid - lane;            // wave*64, wave-uniform
#pragma unroll
  for (int t = 0; t < 5; ++t) {
    int ebase = t * 256 + wbase;     // wave-uniform int4 slot base
    int e = ebase + lane;
    int r = e / 40, qs = e - r * 40;
    int q = qs ^ (r & 7);
    const int4* gsrc = (const int4*)(Fs + (size_t)(jb + r) * D_PAD) + q;
    __builtin_amdgcn_global_load_lds(
        (const __attribute__((address_space(1))) void*)gsrc,
        (__attribute__((address_space(3))) void*)((int4*)buf + ebase),
        16, 0, 0);
  }
}

__global__ __launch_bounds__(256, 3) void pairgroup_kernel(
    const __hip_bfloat16* __restrict__ Fb, const int* __restrict__ labels,
    float* __restrict__ partE, float* __restrict__ sPar,
    float* __restrict__ sAar, int* __restrict__ ticket)
{
  __shared__ __align__(16) char smem[2 * JTILE * D_PAD * 2];   // 40960 B exact
  const short* Fs = (const short*)Fb;
  int tid = threadIdx.x;
  int lane = tid & 63, wave = tid >> 6;
  int g = lane >> 4, lc = lane & 15, sw = lc & 7;
  int bx = blockIdx.x;

  if (bx == 0 && tid == 0) atomicExch(ticket, 0);   // reset for final (device-scope)

  if (bx < NG) {
    // ====== group pass: 64-row i-tiles (global A-frags), 48-row j-tiles =====
    short* Bsg = (short*)smem;                       // [GJT][320], 30720 B
    int* memb = (int*)(smem + 30720);                // 1024 B
    int* cntp = (int*)(smem + 30720 + 1024);         // 4 B   (total 31748)
    int grp = bx + 1;
    if (tid == 0) *cntp = 0;
    __syncthreads();
    for (int i = tid; i < N_ROWS; i += 256)
      if (labels[i] == grp) { int p = atomicAdd(cntp, 1); if (p < 256) memb[p] = i; }
    __syncthreads();
    int c = *cntp; c = c > 256 ? 256 : c;
    int nti = (c + 63) >> 6;               // 64-row i-tiles
    int ntj = (c + GJT - 1) / GJT;         // 48-row j-tiles
    for (int it = 0; it < nti; ++it) {
      short8v afr[10];
      {
        int islot = it * 64 + wave * 16 + lc;
        int arow = memb[islot < c ? islot : 0];
        const short* ap = Fs + (size_t)arow * D_PAD + g * 8;
#pragma unroll
        for (int kk = 0; kk < 10; ++kk) afr[kk] = *(const short8v*)(ap + kk * 32);
      }
      int iglobr[4]; bool ivalid[4];
      for (int r = 0; r < 4; ++r) {
        int islot = it * 64 + wave * 16 + g * 4 + r;
        ivalid[r] = islot < c;
        iglobr[r] = memb[islot < c ? islot : 0];
      }
      float sp[4] = {}, sa[4] = {};
      for (int jt = 0; jt < ntj; ++jt) {
        __syncthreads();
        {
          const int4* src = (const int4*)Fs;
          int4* dst = (int4*)Bsg;
#pragma unroll
          for (int t = 0; t < 8; ++t) {     // 48*40 = 1920 int4 slots
            int e = tid + t * 256;
            if (e < GJT * 40) {
              int r = e / 40, q = e - r * 40;
              int jslot = jt * GJT + r;
              int grow = memb[jslot < c ? jslot : 0];
              dst[r * 40 + (q ^ (r & 7))] = src[(size_t)grow * 40 + q];
            }
          }
        }
        __syncthreads();
        for (int js = 0; js < GJT / 16; ++js) {
          float4v acc = {0.f, 0.f, 0.f, 0.f};
          const short* rowp = Bsg + (js * 16 + lc) * D_PAD;
#pragma unroll
          for (int kk = 0; kk < 10; ++kk) {
            short8v bf = *(const short8v*)(rowp + (((g + 4 * kk) ^ sw) << 3));
            acc = __builtin_amdgcn_mfma_f32_16x16x32_bf16(afr[kk], bf, acc, 0, 0, 0);
          }
          int jslot = jt * GJT + js * 16 + lc;
          bool jv = jslot < c;
          int jglob = memb[jslot < c ? jslot : 0];
#pragma unroll
          for (int r = 0; r < 4; ++r) {
            float a = acc[r];
            float e = exp2f(fmaf(a, LOG2E100, -LOG2E100));
            bool ok = jv && ivalid[r] && (jglob != iglobr[r]);
            sp[r] += ok ? e : 0.f;
            sa[r] += ok ? a : 0.f;
          }
        }
      }
      for (int m = 1; m < 16; m <<= 1)
        for (int r = 0; r < 4; ++r) {
          sp[r] += __shfl_xor(sp[r], m, 64);
          sa[r] += __shfl_xor(sa[r], m, 64);
        }
      if (lc == 0)
        for (int r = 0; r < 4; ++r)
          if (ivalid[r]) { sPar[iglobr[r]] = sp[r]; sAar[iglobr[r]] = sa[r]; }
    }
    return;
  }

  // ========= dense pairwise (round-12 structure EXACTLY, proven) ===========
  short* Bs0 = (short*)smem;                       // [JTILE][320]
  short* Bs1 = (short*)(smem + JTILE * D_PAD * 2); // [JTILE][320]
  int pb = bx - NG;
  int i0 = (pb & 63) * IBLK;
  int split = pb >> 6;
  int jstart = split * JCHUNK;

  // A-frags for 2 i-subtiles of 64 rows each: 80 VGPRs, resident all kernel
  short8v afr[2][10];
#pragma unroll
  for (int s = 0; s < 2; ++s) {
    const short* ap = Fs + (size_t)(i0 + s * 64 + wave * 16 + lc) * D_PAD + g * 8;
#pragma unroll
    for (int kk = 0; kk < 10; ++kk) afr[s][kk] = *(const short8v*)(ap + kk * 32);
  }
  float sE[2][4] = {};

  // prologue: stage jt=0 into buffer 0; __syncthreads drains vmcnt (m97 asm)
  stage_tile32(Fs, jstart, Bs0, tid);
  __syncthreads();

  for (int jt = 0; jt < JCHUNK / JTILE; ++jt) {
    int jb = jstart + jt * JTILE;
    int cur = jt & 1;
    if (jt + 1 < JCHUNK / JTILE)
      stage_tile32(Fs, jb + JTILE, cur ? Bs0 : Bs1, tid);  // async, other buffer

    const short* bufp = cur ? Bs1 : Bs0;
    for (int js = 0; js < JTILE / 16; ++js) {
      float4v acc0 = {0.f, 0.f, 0.f, 0.f}, acc1 = {0.f, 0.f, 0.f, 0.f};
      const short* rowp = bufp + (js * 16 + lc) * D_PAD;
#pragma unroll
      for (int kk = 0; kk < 10; ++kk) {
        short8v bf = *(const short8v*)(rowp + (((g + 4 * kk) ^ sw) << 3));
        acc0 = __builtin_amdgcn_mfma_f32_16x16x32_bf16(afr[0][kk], bf, acc0, 0, 0, 0);
        acc1 = __builtin_amdgcn_mfma_f32_16x16x32_bf16(afr[1][kk], bf, acc1, 0, 0, 0);
      }
      int jgrp = jb + js * 16;   // 16-aligned j-group base
#pragma unroll
      for (int s = 0; s < 2; ++s) {
        float4v acc = s ? acc1 : acc0;
        // diagonal: i-group base == j-group base, then lc == g*4+r inside
        bool dtile = (jgrp == i0 + s * 64 + wave * 16);
#pragma unroll
        for (int r = 0; r < 4; ++r) {
          float e = exp2f(fmaf(acc[r], LOG2E100, -LOG2E100));
          // diagonal excluded here (cannot be reconstructed later without
          // catastrophic cancellation against the ~1e-30-scale sums)
          if (dtile && lc == g * 4 + r) e = 0.0f;
          sE[s][r] += e;
        }
      }
    }
    __syncthreads();   // implicit vmcnt(0) drain: stage(jt+1) has landed
  }

  for (int m = 1; m < 16; m <<= 1)
#pragma unroll
    for (int s = 0; s < 2; ++s)
#pragma unroll
      for (int r = 0; r < 4; ++r) sE[s][r] += __shfl_xor(sE[s][r], m, 64);
  if (lc == 0)
#pragma unroll
    for (int s = 0; s < 2; ++s)
#pragma unroll
      for (int r = 0; r < 4; ++r)
        partE[split * N_ROWS + i0 + s * 64 + wave * 16 + g * 4 + r] = sE[s][r];
}

// ---------- final: per-row combine + last-block ticket scalar reduce ----------
// Per-block LDS histogram of all labels replaces the global counts buffer.
// blk entries padded to 16 floats (64B) so each block's partials live on
// private cache lines; winner reads them with atomicAdd(p,0) (coherence-
// point reads, safe vs non-coherent per-XCD L2s).
__global__ __launch_bounds__(256) void final_kernel(
    const float* __restrict__ partE, const float* __restrict__ sPar,
    const float* __restrict__ sAar, const int* __restrict__ labels,
    float* __restrict__ blk, int* __restrict__ ticket, float* __restrict__ out)
{
  __shared__ int hc[NG + 1];
  __shared__ float rm[256], rv[256];
  __shared__ int winner;
  int tid = threadIdx.x;
  if (tid <= NG) hc[tid] = 0;
  __syncthreads();
  for (int i2 = tid; i2 < N_ROWS; i2 += 256) atomicAdd(&hc[labels[i2]], 1);
  __syncthreads();

  int i = blockIdx.x * 256 + tid;
  float sE = 0.f;
  for (int s = 0; s < NSPLIT; ++s) sE += partE[s * N_ROWS + i];
  float M = 0.f, V = 0.f;
  int pc = hc[labels[i]] - 1;
  if (pc > 0) {
    float P = sPar[i], A = sAar[i];
    float Q = sE - P;
    float pcf = (float)pc, ncf = (float)(N_ROWS - 1 - pc);
    float Z = P / pcf + Q / ncf;
    M = 100.0f * A / pcf - 100.0f - logf(pcf) - logf(Z);
    V = 1.f;
  }
  rm[tid] = M; rv[tid] = V;
  __syncthreads();
  for (int s2 = 128; s2 > 0; s2 >>= 1) {
    if (tid < s2) { rm[tid] += rm[tid + s2]; rv[tid] += rv[tid + s2]; }
    __syncthreads();
  }
  if (tid == 0) {
    blk[blockIdx.x * 16] = rm[0];
    blk[(32 + blockIdx.x) * 16] = rv[0];
    __threadfence();                      // release: partials visible device-wide
    int old = atomicAdd(ticket, 1);
    winner = (old == 31);
  }
  __syncthreads();
  if (winner && tid < 64) {
    float m = (tid < 32) ? atomicAdd(&blk[tid * 16], 0.0f) : 0.f;
    float v = (tid < 32) ? atomicAdd(&blk[(32 + tid) * 16], 0.0f) : 0.f;
    for (int s = 1; s < 32; s <<= 1) {
      m += __shfl_xor(m, s, 64);
      v += __shfl_xor(v, s, 64);
    }
    if (tid == 0) out[0] = (v > 0.f) ? (-TEMP * m / v) : 0.f;
  }
}

extern "C" void kernel_launch(void* const* d_in, const int* in_sizes, int n_in,
                              void* d_out, int out_size, void* d_ws, size_t ws_size,
                              hipStream_t stream)
{
  const float* x  = (const float*)d_in[0];
  const float* W1 = (const float*)d_in[1];
  const float* b1 = (const float*)d_in[2];
  const float* W2 = (const float*)d_in[3];
  const float* b2 = (const float*)d_in[4];
  const int* labels = (const int*)d_in[5];

  char* ws = (char*)d_ws;
  __hip_bfloat16* fb  = (__hip_bfloat16*)(ws);              // 0        .. 5,242,880
  __hip_bfloat16* w1t = (__hip_bfloat16*)(ws + 5242880);    // 204,800
  __hip_bfloat16* w2t = (__hip_bfloat16*)(ws + 5447680);    // 204,800
  float*        partE = (float*)(ws + 5652480);             // 1,048,576
  float*        sPar  = (float*)(ws + 6701056);             // 32,768
  float*        sAar  = (float*)(ws + 6733824);             // 32,768 .. 6,766,592
  // blk/ticket overlay the w1t region (dead after mlp; used only by final)
  float*        blk   = (float*)(ws + 5242880);             // 4,096 B (64 x 16f)
  int*          ticket= (int*)(ws + 5242880 + 4096);        // 4 B

  setup_kernel<<<800, 256, 0, stream>>>(W1, W2, w1t, w2t);
  mlp_fused_kernel<<<N_ROWS / 64, 256, 0, stream>>>(x, w1t, w2t, b1, b2, fb);
  pairgroup_kernel<<<NG + (N_ROWS / IBLK) * NSPLIT, 256, 0, stream>>>(
      fb, labels, partE, sPar, sAar, ticket);
  final_kernel<<<32, 256, 0, stream>>>(partE, sPar, sAar, labels, blk, ticket,
                                       (float*)d_out);
}